// Round 1
// baseline (604.112 us; speedup 1.0000x reference)
//
#include <hip/hip_runtime.h>
#include <math.h>

#define NP 2048      // B*A pairs
#define NN 256       // N
#define HH 128       // H
#define TK 16        // K
#define KHD 2176     // (K+1)*H

// ---------------- k0a: W1 (f64) = norm*Wq*Wk^T ; WmvT = (Wm2 @ Wv^T)^T ; WmT1 = Wm1^T --------
__global__ __launch_bounds__(128)
void k0a(const float* __restrict__ Wq, const float* __restrict__ Wk,
         const float* __restrict__ Wv, const float* __restrict__ Wmot,
         double* __restrict__ W1, float* __restrict__ WmvT, float* __restrict__ WmT1) {
  __shared__ float rowQ[HH];
  __shared__ float rowV[HH];
  const int b = blockIdx.x, t = threadIdx.x;
  rowQ[t] = Wq[b*HH + t];
  rowV[t] = Wv[b*HH + t];
  __syncthreads();
  // W1[b][t] = norm * sum_j Wq[b][j]*Wk[t][j]   (f64)
  double acc = 0.0;
  for (int j = 0; j < HH; ++j) acc += (double)rowQ[j] * (double)Wk[t*HH + j];
  W1[b*HH + t] = acc * 0.08838834764831845;   // 1/sqrt(128)
  // WmvT[i=b][j=t] = sum_k Wmot[j][128+k] * Wv[i][k]
  double acc2 = 0.0;
  for (int k = 0; k < HH; ++k) acc2 += (double)Wmot[t*2*HH + HH + k] * (double)rowV[k];
  WmvT[b*HH + t] = (float)acc2;
  // WmT1[l=b][j=t] = Wmot[j][l]
  WmT1[b*HH + t] = Wmot[t*2*HH + b];
}

// ---------------- k0b: WfT[i][j] = W_fwd[j][i]  (full 2176x128 transpose) ----------------
__global__ __launch_bounds__(128)
void k0b(const float* __restrict__ Wfwd, float* __restrict__ WfT) {
  const int i = blockIdx.x, t = threadIdx.x;
  WfT[i*HH + t] = Wfwd[t*KHD + i];
}

// ---------------- k1: U (f64) = vs@W1 ; Pmot = vs@Wm1^T ; Pfwd = vs@Wf1^T ----------------
__global__ __launch_bounds__(384)
void k1(const float* __restrict__ vs, const double* __restrict__ W1,
        const float* __restrict__ WmT1, const float* __restrict__ WfT,
        double* __restrict__ U, float* __restrict__ Pmot, float* __restrict__ Pfwd) {
  __shared__ float vs_s[8][HH];
  const int b = blockIdx.x, t = threadIdx.x;
  const int p0 = b*8;
  for (int i = t; i < 8*HH; i += 384) vs_s[i>>7][i&127] = vs[(size_t)p0*HH + i];
  __syncthreads();
  const int which = t >> 7, col = t & 127;
  if (which == 0) {
    double acc[8] = {0,0,0,0,0,0,0,0};
    for (int l = 0; l < HH; ++l) {
      const double w = W1[l*HH + col];
      #pragma unroll
      for (int m = 0; m < 8; ++m) acc[m] += (double)vs_s[m][l] * w;
    }
    #pragma unroll
    for (int m = 0; m < 8; ++m) U[(size_t)(p0+m)*HH + col] = acc[m];
  } else {
    const float* Wp = (which == 1) ? WmT1 : WfT;   // WfT rows 0..127 = vs-part of W_fwd
    float acc[8] = {0,0,0,0,0,0,0,0};
    for (int l = 0; l < HH; ++l) {
      const float w = Wp[l*HH + col];
      #pragma unroll
      for (int m = 0; m < 8; ++m) acc[m] += vs_s[m][l] * w;
    }
    float* out = (which == 1) ? Pmot : Pfwd;
    #pragma unroll
    for (int m = 0; m < 8; ++m) out[(size_t)(p0+m)*HH + col] = acc[m];
  }
}

// ---------------- kb: main streaming kernel, one block per (b,a) pair ----------------
// ve (256x128 f32) -> LDS; compat (f64) during load; mask+softmax; s_v; v_M; top-k; VC gather
__global__ __launch_bounds__(512)
void kb(const float* __restrict__ ve, const int* __restrict__ ve_dead,
        const double* __restrict__ U, const float* __restrict__ Pmot,
        const float* __restrict__ b_mot, const float* __restrict__ WmvT,
        float* __restrict__ VC, float* __restrict__ outM) {
  __shared__ float  ve_s[NN*HH];   // 128 KB, linear: row-reads by block, col-reads coalesced
  __shared__ double compat[NN];
  __shared__ float  e_s[NN];
  __shared__ float  svp[4*HH];
  __shared__ float  red[8];
  __shared__ int    tix[TK];

  const int p = blockIdx.x, t = threadIdx.x;
  const int c = t & 31;
  const double* up = U + (size_t)p*HH + 4*c;
  const double u0 = up[0], u1 = up[1], u2 = up[2], u3 = up[3];
  const float4* src = (const float4*)(ve + (size_t)p*NN*HH);
  float4* dst = (float4*)ve_s;
  #pragma unroll 4
  for (int k = 0; k < 16; ++k) {
    const int idx = k*512 + t;              // coalesced float4 stream
    const float4 v = src[idx];
    dst[idx] = v;
    double part = (double)v.x*u0 + (double)v.y*u1 + (double)v.z*u2 + (double)v.w*u3;
    part += __shfl_xor(part, 16, 32);
    part += __shfl_xor(part, 8, 32);
    part += __shfl_xor(part, 4, 32);
    part += __shfl_xor(part, 2, 32);
    part += __shfl_xor(part, 1, 32);
    if (c == 0) compat[idx >> 5] = part;    // row = idx/32
  }
  __syncthreads();

  // mask + per-thread value
  float cf = -INFINITY;
  if (t < NN) {
    double cd = compat[t];
    if (ve_dead[(size_t)p*NN + t] != 0) { cd = -INFINITY; compat[t] = cd; }
    cf = (float)cd;
  }
  // block max (waves 4..7 contribute -inf)
  float mval = cf;
  #pragma unroll
  for (int off = 32; off; off >>= 1) mval = fmaxf(mval, __shfl_xor(mval, off, 64));
  if ((t & 63) == 0) red[t >> 6] = mval;
  __syncthreads();
  float mx = red[0];
  #pragma unroll
  for (int w = 1; w < 8; ++w) mx = fmaxf(mx, red[w]);
  __syncthreads();                          // red about to be reused
  float e = 0.f;
  if (t < NN && mx != -INFINITY) e = expf(cf - mx);
  if (t < NN) e_s[t] = e;
  float s = e;
  #pragma unroll
  for (int off = 32; off; off >>= 1) s += __shfl_xor(s, off, 64);
  if ((t & 63) == 0) red[t >> 6] = s;
  __syncthreads();
  float ssum = 0.f;
  #pragma unroll
  for (int w = 0; w < 8; ++w) ssum += red[w];
  const float inv = (ssum > 0.f) ? 1.f/ssum : 0.f;   // all-masked -> 0 (nan_to_num)

  // s_v partials: seg = t>>7 covers 64 rows; column reads conflict-free
  {
    const int seg = t >> 7, h = t & 127;
    float acc = 0.f;
    const int n0 = seg*64;
    for (int n = n0; n < n0+64; ++n) acc += e_s[n] * ve_s[n*HH + h];
    svp[seg*HH + h] = acc;
  }
  __syncthreads();
  if (t < HH) e_s[t] = inv * (svp[t] + svp[HH+t] + svp[2*HH+t] + svp[3*HH+t]); // s_v
  __syncthreads();

  if (t < HH) {
    // v_M_final = relu(Pmot + b_mot + WmvT^T s_v)
    float acc = Pmot[(size_t)p*HH + t] + b_mot[t];
    for (int i = 0; i < HH; ++i) acc += e_s[i] * WmvT[i*HH + t];
    outM[(size_t)p*HH + t] = fmaxf(acc, 0.f);
  } else if (t >= 448) {
    // wave 7: top-16 by f64 compat, stable (lower index wins ties) — matches lax.top_k
    const int lane = t - 448;
    double v0 = compat[lane], v1 = compat[64+lane], v2 = compat[128+lane], v3 = compat[192+lane];
    int used = 0;
    for (int k = 0; k < TK; ++k) {
      double bv = 0.0; int bi = 1<<30;
      if (!(used&1))                               { bv = v0; bi = lane; }
      if (!(used&2) && (bi==(1<<30) || v1 > bv))   { bv = v1; bi = 64+lane; }
      if (!(used&4) && (bi==(1<<30) || v2 > bv))   { bv = v2; bi = 128+lane; }
      if (!(used&8) && (bi==(1<<30) || v3 > bv))   { bv = v3; bi = 192+lane; }
      #pragma unroll
      for (int off = 32; off; off >>= 1) {
        const double ov = __shfl_xor(bv, off, 64);
        const int    oi = __shfl_xor(bi, off, 64);
        if (oi != (1<<30) && (bi == (1<<30) || ov > bv || (ov == bv && oi < bi))) { bv = ov; bi = oi; }
      }
      if (lane == 0) tix[k] = bi;
      if ((bi & 63) == lane) used |= 1 << (bi >> 6);   // remove winner from its owner lane
    }
  }
  __syncthreads();
  // gather top-K ve rows (in rank order) to compact VC for the v_C GEMM
  float* vc = VC + (size_t)p*TK*HH;
  for (int i = t; i < TK*HH; i += 512) vc[i] = ve_s[tix[i >> 7]*HH + (i & 127)];
}

// ---------------- k3: v_C_final GEMM: out = relu(Pfwd + b_fwd + VC @ WfT[128:,:]) --------
__global__ __launch_bounds__(512)
void k3(const float* __restrict__ VC, const float* __restrict__ WfT,
        const float* __restrict__ Pfwd, const float* __restrict__ b_fwd,
        float* __restrict__ outC) {
  __shared__ float A_s[8*2048];   // 8 pairs x (16 rows * 128) = 64 KB
  const int b = blockIdx.x, t = threadIdx.x;
  const int p0 = b*8;
  const float4* src = (const float4*)(VC + (size_t)p0*2048);
  float4* dst = (float4*)A_s;
  for (int i = t; i < 4096; i += 512) dst[i] = src[i];
  __syncthreads();
  const int j = t & 127, mg = t >> 7;
  const int pa = 2*mg, pb = 2*mg + 1;
  float acc0 = Pfwd[(size_t)(p0+pa)*HH + j] + b_fwd[j];
  float acc1 = Pfwd[(size_t)(p0+pb)*HH + j] + b_fwd[j];
  const float* w  = WfT + HH*HH + j;      // rows 128.. of WfT (gathered part)
  const float* a0 = A_s + pa*2048;
  const float* a1 = A_s + pb*2048;
  for (int i = 0; i < 2048; i += 4) {
    const float4 x0 = *(const float4*)(a0 + i);   // LDS broadcast
    const float4 x1 = *(const float4*)(a1 + i);
    const float w0 = w[(i+0)*HH], w1 = w[(i+1)*HH], w2 = w[(i+2)*HH], w3 = w[(i+3)*HH];
    acc0 += x0.x*w0; acc0 += x0.y*w1; acc0 += x0.z*w2; acc0 += x0.w*w3;
    acc1 += x1.x*w0; acc1 += x1.y*w1; acc1 += x1.z*w2; acc1 += x1.w*w3;
  }
  outC[(size_t)(p0+pa)*HH + j] = fmaxf(acc0, 0.f);
  outC[(size_t)(p0+pb)*HH + j] = fmaxf(acc1, 0.f);
}

extern "C" void kernel_launch(void* const* d_in, const int* in_sizes, int n_in,
                              void* d_out, int out_size, void* d_ws, size_t ws_size,
                              hipStream_t stream) {
  const float* vs   = (const float*)d_in[0];
  const float* ve   = (const float*)d_in[1];
  const int*   vd   = (const int*)  d_in[2];
  const float* Wq   = (const float*)d_in[3];
  const float* Wk   = (const float*)d_in[4];
  const float* Wv   = (const float*)d_in[5];
  const float* Wmot = (const float*)d_in[6];
  const float* bmot = (const float*)d_in[7];
  const float* Wfwd = (const float*)d_in[8];
  const float* bfwd = (const float*)d_in[9];

  char* ws = (char*)d_ws;
  double* W1  = (double*)(ws + 0);        // 128*128*8  = 131072
  float* WmvT = (float*)(ws + 131072);    // 65536
  float* WmT1 = (float*)(ws + 196608);    // 65536
  float* WfT  = (float*)(ws + 262144);    // 2176*128*4 = 1114112
  double* U   = (double*)(ws + 1376256);  // 2048*128*8 = 2097152
  float* Pmot = (float*)(ws + 3473408);   // 1048576
  float* Pfwd = (float*)(ws + 4521984);   // 1048576
  float* VC   = (float*)(ws + 5570560);   // 2048*2048*4 = 16777216 (ends 22347776)

  float* outC = (float*)d_out;
  float* outM = outC + (size_t)NP*HH;

  k0a<<<128, 128, 0, stream>>>(Wq, Wk, Wv, Wmot, W1, WmvT, WmT1);
  k0b<<<KHD, 128, 0, stream>>>(Wfwd, WfT);
  k1 <<<256, 384, 0, stream>>>(vs, W1, WmT1, WfT, U, Pmot, Pfwd);
  kb <<<NP, 512, 0, stream>>>(ve, vd, U, Pmot, bmot, WmvT, VC, outM);
  k3 <<<256, 512, 0, stream>>>(VC, WfT, Pfwd, bfwd, outC);
}